// Round 4
// baseline (140.467 us; speedup 1.0000x reference)
//
#include <hip/hip_runtime.h>
#include <cstdint>
#include <cstddef>

// Problem dims
#define B_ROWS 65536
#define D_IN   784
#define KP     800      // D_IN padded to multiple of 32
#define D_H    300
#define NP     320      // D_H padded to multiple of 64
#define D_OUT  10
#define NP2    16       // D_OUT padded to 16
#define EPS    1e-5f
#define NBLK   1024     // blocks in gemm1 and gemm2 grids
#define APAD   44       // LDS A row stride in halfs (proven low-conflict)

typedef _Float16 half8  __attribute__((ext_vector_type(8)));
typedef _Float16 half4  __attribute__((ext_vector_type(4)));
typedef float    floatx4 __attribute__((ext_vector_type(4)));

// Workspace layout (bytes). part[] aliases oc[]: part is consumed by k_reduce
// BEFORE k_gemm2 writes oc (strictly ordered on one stream).
#define OFF_S1   ((size_t)0)                       // _Float16[320*800]   = 512000
#define OFF_H    ((size_t)512000)                  // _Float16[65536*320] = 41943040
#define OFF_ST1  (OFF_H + (size_t)41943040)        // float[640]
#define OFF_W2   (OFF_ST1 + (size_t)2560)          // _Float16[16*320]    = 10240
#define OFF_ST2  (OFF_W2 + (size_t)10240)          // float[32]
#define OFF_OC   (OFF_ST2 + (size_t)256)           // float[65536*16]     = 4194304
#define OFF_P1   OFF_OC                            // float[640][1024] (alias, time-disjoint)
#define OFF_P2   (OFF_OC + (size_t)4194304)        // float[32][1024]     = 131072

// ---------------- K0: binarize W1 -> fp16 (+-1), zero-padded to [320][800]
__global__ void k_prep1(const float* __restrict__ W1, _Float16* __restrict__ S1)
{
    int idx = blockIdx.x * 256 + threadIdx.x;      // 0..255999
    int n = idx / KP;
    int k = idx - n * KP;
    float v = 0.0f;
    if (n < D_H && k < D_IN)
        v = (W1[n * D_IN + k] >= 0.0f) ? 1.0f : -1.0f;
    S1[idx] = (_Float16)v;
}

// ---------------- K1: h = x @ S1^T  (M=65536, N=320, K=800), fp16 MFMA
// OCCUPANCY variant. Rounds 1-3 proved the 120us plateau is invariant to
// pipeline structure; the invariant was 2 waves/SIMD (acc[4][5]=80 AGPR +
// ~100 VGPR = ~190 unified regs). Here: 512 threads, 8 waves in a 2(M)x4(N)
// grid, each wave 32 rows x 80 cols -> acc[2][5]=40 AGPR, ~115-125 unified
// -> 3-4 waves/SIMD (37-50% occupancy) to actually hide the L2/L3-miss
// latency. Loop skeleton = round-2's proven one (BK=32, stride-44 LDS
// double-buffer, depth-2 x register prefetch, raw lgkm-only barrier).
// Cost: B frags loaded by 2 waves each (2x B L2 traffic, well under L2 BW);
// per-block stats need a cross-wave-pair LDS combine in the epilogue.

#define PF_B(BV, NK)                                                        \
    _Pragma("unroll")                                                       \
    for (int nt = 0; nt < 5; ++nt)                                          \
        BV[nt] = *(const half8*)(bb + (size_t)nt * 16 * KP + (NK));

// thread t stages 4 fp32 cols [KK+scol, KK+scol+4) of row t>>3; D_IN%4==0
// so the guard is all-or-nothing per chunk (zeros for the k>=784 pad).
#define STAGE_LOAD(V, KK)                                                   \
    {                                                                       \
        V = (floatx4){};                                                    \
        if ((KK) + scol < D_IN)                                             \
            V = *(const floatx4*)(sxp + (KK));                              \
    }

#define STAGE_STORE(V, BUF)                                                 \
    {                                                                       \
        half4 hv;                                                           \
        _Pragma("unroll")                                                   \
        for (int j = 0; j < 4; ++j) hv[j] = (_Float16)V[j];                 \
        *(half4*)&Alds[BUF][srow][scol] = hv;                               \
    }

#define AFRAG(BUF)                                                          \
    _Pragma("unroll")                                                       \
    for (int mt = 0; mt < 2; ++mt)                                          \
        a[mt] = *(const half8*)&Alds[BUF][wm * 32 + mt * 16 + row15][quad * 8];

#define COMPUTE(BV)                                                         \
    _Pragma("unroll")                                                       \
    for (int nt = 0; nt < 5; ++nt)                                          \
        _Pragma("unroll")                                                   \
        for (int mt = 0; mt < 2; ++mt)                                      \
            acc[mt][nt] = __builtin_amdgcn_mfma_f32_16x16x32_f16(           \
                a[mt], BV[nt], acc[mt][nt], 0, 0, 0);

// Publish LDS writes WITHOUT draining vmcnt (in-flight global loads survive
// the barrier); sched fences pin memory ops on their side.
#define BAR()                                                               \
    asm volatile("s_waitcnt lgkmcnt(0)" ::: "memory");                      \
    __builtin_amdgcn_sched_barrier(0);                                      \
    __builtin_amdgcn_s_barrier();                                           \
    __builtin_amdgcn_sched_barrier(0);

__global__ __launch_bounds__(512, 3) void k_gemm1(const float* __restrict__ x,
                                                  const _Float16* __restrict__ S1,
                                                  _Float16* __restrict__ h,
                                                  float* __restrict__ part)
{
    __shared__ _Float16 Alds[2][64][APAD];   // 2 x 5.5 KB
    const int t     = threadIdx.x;
    const int wave  = t >> 6;
    const int lane  = t & 63;
    const int row15 = lane & 15;
    const int quad  = lane >> 4;
    const int wm    = wave >> 2;         // 0..1: M half (32 rows)
    const int wn    = wave & 3;          // 0..3: N slice (80 cols)
    const int m0    = blockIdx.x * 64;

    // staging: thread t -> row t>>3, 4-col chunk (t&7)*4  (64 rows x 32 cols)
    const int srow  = t >> 3;
    const int scol  = (t & 7) * 4;
    const float* sxp = x + (size_t)(m0 + srow) * D_IN + scol;

    // B fragment base (MFMA B layout: lane holds col=row15, k=quad*8..+8)
    const _Float16* bb = S1 + (size_t)(wn * 80 + row15) * KP + quad * 8;

    floatx4 acc[2][5] = {};
    half8   b0[5], b1[5];
    half8   a[2];
    floatx4 svA, svB;                    // depth-2 x prefetch register sets

    // prologue: buf0 <- x(0); svB <- x(1) in flight; b0 <- B(0)
    STAGE_LOAD(svA, 0)
    PF_B(b0, 0)
    STAGE_LOAD(svB, 32)
    STAGE_STORE(svA, 0)                  // counted vmcnt: waits only svA
    BAR()

    for (int i = 0; i < 12; ++i) {
        const int kk = i * 64;
        // even step s=2i: reads buf0/b0; svB holds x(s+1); issue x(s+2)->svA
        STAGE_LOAD(svA, kk + 64)
        PF_B(b1, kk + 32)
        AFRAG(0)
        COMPUTE(b0)
        STAGE_STORE(svB, 1)
        BAR()
        // odd step s=2i+1: reads buf1/b1; svA holds x(s+1); issue x(s+2)->svB
        STAGE_LOAD(svB, kk + 96)         // i=11 -> 800: guard kills all loads
        PF_B(b0, kk + 64)                // i=11 -> B(24) at koff 768
        AFRAG(1)
        COMPUTE(b1)
        STAGE_STORE(svA, 0)
        BAR()
    }
    // tail step 24: reads buf0/b0 (k = 768..799, pad lanes hit B zeros)
    AFRAG(0)
    COMPUTE(b0)

    // --- epilogue: store h (C/D layout: col=lane&15, row=quad*4+r) + stats
    float s[5] = {}, q[5] = {};
#pragma unroll
    for (int mt = 0; mt < 2; ++mt)
#pragma unroll
        for (int nt = 0; nt < 5; ++nt)
#pragma unroll
            for (int r = 0; r < 4; ++r) {
                float v = acc[mt][nt][r];
                int m = m0 + wm * 32 + mt * 16 + quad * 4 + r;
                int n = wn * 80 + nt * 16 + row15;
                h[(size_t)m * NP + n] = (_Float16)v;
                s[nt] += v;
                q[nt] += v * v;
            }
    // reduce over quad within the wave
#pragma unroll
    for (int nt = 0; nt < 5; ++nt) {
        s[nt] += __shfl_xor(s[nt], 16); s[nt] += __shfl_xor(s[nt], 32);
        q[nt] += __shfl_xor(q[nt], 16); q[nt] += __shfl_xor(q[nt], 32);
    }
    // combine the wave pair (wm=0/1) sharing each N slice via LDS (reuse Alds)
    float* red = (float*)&Alds[0][0][0];         // 640 floats needed, 11K avail
    __syncthreads();                             // main-loop LDS reads done
    if (wm == 1 && quad == 0) {
#pragma unroll
        for (int nt = 0; nt < 5; ++nt) {
            int cl = wn * 80 + nt * 16 + row15;
            red[cl]       = s[nt];
            red[320 + cl] = q[nt];
        }
    }
    __syncthreads();
    if (wm == 0 && quad == 0) {
#pragma unroll
        for (int nt = 0; nt < 5; ++nt) {
            int cl = wn * 80 + nt * 16 + row15;
            part[(size_t)cl * NBLK + blockIdx.x]        = s[nt] + red[cl];
            part[(size_t)(NP + cl) * NBLK + blockIdx.x] = q[nt] + red[320 + cl];
        }
    }
}

// ---------------- K2: contention-free reduce of per-block partials
// (one block per output element; partial stride fixed at NBLK=1024)
__global__ void k_reduce(const float* __restrict__ part, float* __restrict__ st)
{
    __shared__ float red[4];
    const int c = blockIdx.x;
    const int t = threadIdx.x;           // 256
    const float* p = part + (size_t)c * NBLK;
    float s = p[t] + p[t + 256] + p[t + 512] + p[t + 768];
#pragma unroll
    for (int off = 1; off < 64; off <<= 1) s += __shfl_xor(s, off);
    if ((t & 63) == 0) red[t >> 6] = s;
    __syncthreads();
    if (t == 0) st[c] = red[0] + red[1] + red[2] + red[3];
}

// ---------------- K3: fold BN1 scale into binarized W2 -> w2h[16][320] fp16
__global__ void k_prep2(const float* __restrict__ st, const float* __restrict__ gamma1,
                        const float* __restrict__ W2, _Float16* __restrict__ w2h)
{
    int j = threadIdx.x;                 // 0..319
    float mean = st[j] * (1.0f / 65536.0f);
    float var  = st[NP + j] * (1.0f / 65536.0f) - mean * mean;
    float a1   = 0.0f;
    if (j < D_H) a1 = gamma1[j] / sqrtf(var + EPS);
    for (int k = 0; k < NP2; ++k) {
        float w = 0.0f;
        if (k < D_OUT && j < D_H)
            w = (W2[k * D_H + j] >= 0.0f) ? a1 : -a1;
        w2h[k * NP + j] = (_Float16)w;
    }
}

// ---------------- K4: oc = h @ w2h^T  (K=320, N=16) + per-block stat partials
__global__ __launch_bounds__(256) void k_gemm2(const _Float16* __restrict__ h,
                                               const _Float16* __restrict__ w2h,
                                               float* __restrict__ oc,
                                               float* __restrict__ part2)
{
    __shared__ _Float16 Wlds[16][328];   // pad 320->328 to break bank conflicts
    __shared__ float reds[4][16], redq[4][16];
    const int t     = threadIdx.x;
    const int wave  = t >> 6;
    const int lane  = t & 63;
    const int row15 = lane & 15;
    const int quad  = lane >> 4;

    for (int c = t; c < 640; c += 256) { // 16*320/8 chunks
        int r  = c / 40;
        int cc = (c - r * 40) * 8;
        *(half8*)&Wlds[r][cc] = *(const half8*)(w2h + r * NP + cc);
    }
    __syncthreads();

    const int m0 = blockIdx.x * 64 + wave * 16;
    const _Float16* hp = h + (size_t)(m0 + row15) * NP + quad * 8;
    floatx4 acc = {};
#pragma unroll
    for (int kk = 0; kk < NP; kk += 32) {
        half8 a2 = *(const half8*)(hp + kk);
        half8 b2 = *(const half8*)&Wlds[row15][kk + quad * 8];
        acc = __builtin_amdgcn_mfma_f32_16x16x32_f16(a2, b2, acc, 0, 0, 0);
    }
    float s = 0.f, q = 0.f;
#pragma unroll
    for (int r = 0; r < 4; ++r) {
        float v = acc[r];
        oc[(size_t)(m0 + quad * 4 + r) * NP2 + row15] = v;
        s += v; q += v * v;
    }
    s += __shfl_xor(s, 16); s += __shfl_xor(s, 32);
    q += __shfl_xor(q, 16); q += __shfl_xor(q, 32);
    if (lane < 16) { reds[wave][row15] = s; redq[wave][row15] = q; }
    __syncthreads();
    if (t < 16) {
        float S = reds[0][t] + reds[1][t] + reds[2][t] + reds[3][t];
        float Q = redq[0][t] + redq[1][t] + redq[2][t] + redq[3][t];
        part2[(size_t)t * NBLK + blockIdx.x]          = S;
        part2[(size_t)(16 + t) * NBLK + blockIdx.x]   = Q;
    }
}

// ---------------- K5: BN2 epilogue -> out[65536][10] fp32
__global__ void k_final(const float* __restrict__ oc, const float* __restrict__ st2,
                        const float* __restrict__ gamma2, const float* __restrict__ beta2,
                        float* __restrict__ out)
{
    int idx = blockIdx.x * 256 + threadIdx.x;    // 2560*256 == 655360 exactly
    int m = idx / 10;
    int k = idx - m * 10;
    float mean = st2[k] * (1.0f / 65536.0f);
    float var  = st2[16 + k] * (1.0f / 65536.0f) - mean * mean;
    float sc   = gamma2[k] / sqrtf(var + EPS);
    out[idx] = (oc[(size_t)m * NP2 + k] - mean) * sc + beta2[k];
}

extern "C" void kernel_launch(void* const* d_in, const int* in_sizes, int n_in,
                              void* d_out, int out_size, void* d_ws, size_t ws_size,
                              hipStream_t stream)
{
    const float* x      = (const float*)d_in[0];
    const float* W1     = (const float*)d_in[1];
    const float* gamma1 = (const float*)d_in[2];
    // d_in[3] = beta1 : algebraically cancels under BN2's mean subtraction
    const float* W2     = (const float*)d_in[4];
    const float* gamma2 = (const float*)d_in[5];
    const float* beta2  = (const float*)d_in[6];
    float* out = (float*)d_out;

    char* ws = (char*)d_ws;
    _Float16* S1    = (_Float16*)(ws + OFF_S1);
    _Float16* h     = (_Float16*)(ws + OFF_H);
    float*    st1   = (float*)(ws + OFF_ST1);
    _Float16* w2h   = (_Float16*)(ws + OFF_W2);
    float*    st2   = (float*)(ws + OFF_ST2);
    float*    oc    = (float*)(ws + OFF_OC);
    float*    part  = (float*)(ws + OFF_P1);   // aliases oc (time-disjoint)
    float*    part2 = (float*)(ws + OFF_P2);

    k_prep1 <<<1000, 256, 0, stream>>>(W1, S1);
    k_gemm1 <<<NBLK, 512, 0, stream>>>(x, S1, h, part);
    k_reduce<<<640, 256, 0, stream>>>(part, st1);
    k_prep2 <<<1, 320, 0, stream>>>(st1, gamma1, W2, w2h);
    k_gemm2 <<<NBLK, 256, 0, stream>>>(h, w2h, oc, part2);
    k_reduce<<<32, 256, 0, stream>>>(part2, st2);
    k_final <<<2560, 256, 0, stream>>>(oc, st2, gamma2, beta2, out);
}

// Round 5
// 103.913 us; speedup vs baseline: 1.3518x; 1.3518x over previous
//
#include <hip/hip_runtime.h>
#include <cstdint>
#include <cstddef>

// Problem dims
#define B_ROWS 65536
#define D_IN   784
#define KP     800      // D_IN padded to multiple of 32
#define D_H    300
#define NP     320      // D_H padded to multiple of 64
#define D_OUT  10
#define NP2    16       // D_OUT padded to 16
#define EPS    1e-5f
#define NBLK   1024     // blocks in gemm1 and gemm2 grids
#define APAD   44       // LDS A row stride in halfs (44*2=88 B -> <=2-way banks)

typedef _Float16 half8  __attribute__((ext_vector_type(8)));
typedef float    floatx4 __attribute__((ext_vector_type(4)));

// Workspace layout (bytes). part[] aliases oc[]: part is consumed by k_stat1
// BEFORE k_gemm2 writes oc (strictly ordered on one stream).
#define OFF_S1   ((size_t)0)                       // _Float16[320*800]   = 512000
#define OFF_H    ((size_t)512000)                  // _Float16[65536*320] = 41943040
#define OFF_ST1  (OFF_H + (size_t)41943040)        // float[640] (unused, layout keep)
#define OFF_W2   (OFF_ST1 + (size_t)2560)          // _Float16[16*320]    = 10240
#define OFF_ST2  (OFF_W2 + (size_t)10240)          // float[32]
#define OFF_OC   (OFF_ST2 + (size_t)256)           // float[65536*16]     = 4194304
#define OFF_P1   OFF_OC                            // float[640][1024] (alias, time-disjoint)
#define OFF_P2   (OFF_OC + (size_t)4194304)        // float[32][1024]     = 131072

// ---------------- K0: binarize W1 -> fp16 (+-1), zero-padded to [320][800]
__global__ void k_prep1(const float* __restrict__ W1, _Float16* __restrict__ S1)
{
    int idx = blockIdx.x * 256 + threadIdx.x;      // 0..255999
    int n = idx / KP;
    int k = idx - n * KP;
    float v = 0.0f;
    if (n < D_H && k < D_IN)
        v = (W1[n * D_IN + k] >= 0.0f) ? 1.0f : -1.0f;
    S1[idx] = (_Float16)v;
}

// ---------------- K1: h = x @ S1^T  (M=65536, N=320, K=800), fp16 MFMA
// EXACT round-0 structure (best wall-verified: 95.0us). A staged ONCE per
// block into double-buffered LDS (fp32 load -> cvt -> fp16 ds_write), one
// barrier per 32-wide K-step; A-frags via ds_read_b128 from padded rows
// (stride 44 halfs). B (L2-resident 512 KB) prefetched into compile-time
// ping-pong register sets. Fused per-block column sum/sumsq partials of h.
// NOTE (rounds 1-4): barrier-free, counted-vmcnt, BK=64, and 2x-occupancy
// variants all measured neutral-to-worse; this 2-phase structure's ceiling
// is the stage+barrier critical path (cf. m233) - do not re-litigate
// without a full 8-phase port.

#define PF_B(BV, NK)                                                        \
    _Pragma("unroll")                                                       \
    for (int nt = 0; nt < 5; ++nt)                                          \
        BV[nt] = *(const half8*)(bb + (size_t)nt * 16 * KP + (NK));

#define STAGE_LOAD(KK)                                                      \
    {                                                                       \
        sv0 = (floatx4){}; sv1 = (floatx4){};                               \
        if ((KK) + sc < D_IN) {            /* chunk-uniform: D_IN%8==0 */   \
            sv0 = *(const floatx4*)(sxp + (KK));                            \
            sv1 = *(const floatx4*)(sxp + (KK) + 4);                        \
        }                                                                   \
    }

#define STAGE_STORE(BUF)                                                    \
    {                                                                       \
        half8 hv;                                                           \
        _Pragma("unroll")                                                   \
        for (int i2 = 0; i2 < 4; ++i2) {                                    \
            hv[i2]     = (_Float16)sv0[i2];                                 \
            hv[4 + i2] = (_Float16)sv1[i2];                                 \
        }                                                                   \
        *(half8*)&Alds[BUF][srow][sc] = hv;                                 \
    }

#define AFRAG(BUF)                                                          \
    _Pragma("unroll")                                                       \
    for (int mt = 0; mt < 4; ++mt)                                          \
        a[mt] = *(const half8*)&Alds[BUF][mt * 16 + row15][quad * 8];

#define COMPUTE(BV)                                                         \
    _Pragma("unroll")                                                       \
    for (int nt = 0; nt < 5; ++nt)                                          \
        _Pragma("unroll")                                                   \
        for (int mt = 0; mt < 4; ++mt)                                      \
            acc[mt][nt] = __builtin_amdgcn_mfma_f32_16x16x32_f16(           \
                a[mt], BV[nt], acc[mt][nt], 0, 0, 0);

__global__ __launch_bounds__(256) void k_gemm1(const float* __restrict__ x,
                                               const _Float16* __restrict__ S1,
                                               _Float16* __restrict__ h,
                                               float* __restrict__ part)
{
    __shared__ _Float16 Alds[2][64][APAD];   // 2 x 5.5 KB
    const int t     = threadIdx.x;
    const int wave  = t >> 6;
    const int lane  = t & 63;
    const int row15 = lane & 15;
    const int quad  = lane >> 4;
    const int m0    = blockIdx.x * 64;

    // staging assignment: thread t -> row t>>2, half-chunk (t&3)*8
    const int srow = t >> 2;
    const int sc   = (t & 3) * 8;
    const float* sxp = x + (size_t)(m0 + srow) * D_IN + sc;

    // B fragment base (MFMA B layout: lane holds col=row15, k=quad*8..+8)
    const _Float16* bb = S1 + (size_t)(wave * 80 + row15) * KP + quad * 8;

    floatx4 acc[4][5] = {};
    half8   b0[5], b1[5];
    half8   a[4];
    floatx4 sv0, sv1;

    STAGE_LOAD(0)
    STAGE_STORE(0)
    PF_B(b0, 0)
    __syncthreads();

    for (int i = 0; i < 12; ++i) {
        const int kk = i * 64;
        // even step 2i: reads Alds[0] / b0; stages step 2i+1 -> Alds[1]
        STAGE_LOAD(kk + 32)
        PF_B(b1, kk + 32)
        AFRAG(0)
        COMPUTE(b0)
        STAGE_STORE(1)
        __syncthreads();
        // odd step 2i+1: reads Alds[1] / b1; stages step 2i+2 -> Alds[0]
        STAGE_LOAD(kk + 64)            // i=11 -> 768 (tail chunks zero-padded)
        PF_B(b0, kk + 64)
        AFRAG(1)
        COMPUTE(b1)
        STAGE_STORE(0)
        __syncthreads();
    }
    // tail step 24: reads Alds[0] / b0
    AFRAG(0)
    COMPUTE(b0)

    // --- epilogue: store h (C/D layout: col=lane&15, row=quad*4+r) + stats
    float s[5] = {}, q[5] = {};
#pragma unroll
    for (int mt = 0; mt < 4; ++mt)
#pragma unroll
        for (int nt = 0; nt < 5; ++nt)
#pragma unroll
            for (int r = 0; r < 4; ++r) {
                float v = acc[mt][nt][r];
                int m = m0 + mt * 16 + quad * 4 + r;
                int n = wave * 80 + nt * 16 + row15;
                h[(size_t)m * NP + n] = (_Float16)v;
                s[nt] += v;
                q[nt] += v * v;
            }
    // reduce over quad (waves own disjoint col ranges -> no cross-wave combine)
#pragma unroll
    for (int nt = 0; nt < 5; ++nt) {
        s[nt] += __shfl_xor(s[nt], 16); s[nt] += __shfl_xor(s[nt], 32);
        q[nt] += __shfl_xor(q[nt], 16); q[nt] += __shfl_xor(q[nt], 32);
    }
    if (quad == 0) {
#pragma unroll
        for (int nt = 0; nt < 5; ++nt) {
            int col = wave * 80 + nt * 16 + row15;
            part[(size_t)col * NBLK + blockIdx.x]        = s[nt];
            part[(size_t)(NP + col) * NBLK + blockIdx.x] = q[nt];
        }
    }
}

// ---------------- K2: FUSED reduce + BN1-fold-into-W2 (was k_reduce + k_prep2)
// One block per hidden col j: reduce sum AND sumsq partials, then threads
// 0..15 write the BN1-scaled binarized W2 column. Removes one dispatch and
// the old 1-block k_prep2 serialization bubble. Same reduction order and
// same gamma1/sqrtf(var+EPS) formula as before (numerics identical).
__global__ void k_stat1(const float* __restrict__ part, const float* __restrict__ gamma1,
                        const float* __restrict__ W2, _Float16* __restrict__ w2h)
{
    __shared__ float redS[4], redQ[4];
    const int j = blockIdx.x;            // 0..319
    const int t = threadIdx.x;           // 256
    const float* ps = part + (size_t)j * NBLK;
    const float* pq = part + (size_t)(NP + j) * NBLK;
    float s = ps[t] + ps[t + 256] + ps[t + 512] + ps[t + 768];
    float q = pq[t] + pq[t + 256] + pq[t + 512] + pq[t + 768];
#pragma unroll
    for (int off = 1; off < 64; off <<= 1) {
        s += __shfl_xor(s, off);
        q += __shfl_xor(q, off);
    }
    if ((t & 63) == 0) { redS[t >> 6] = s; redQ[t >> 6] = q; }
    __syncthreads();
    if (t < NP2) {
        float S = redS[0] + redS[1] + redS[2] + redS[3];
        float Q = redQ[0] + redQ[1] + redQ[2] + redQ[3];
        float mean = S * (1.0f / 65536.0f);
        float var  = Q * (1.0f / 65536.0f) - mean * mean;
        float a1   = 0.0f;
        if (j < D_H) a1 = gamma1[j] / sqrtf(var + EPS);
        float w = 0.0f;
        if (t < D_OUT && j < D_H)
            w = (W2[t * D_H + j] >= 0.0f) ? a1 : -a1;
        w2h[t * NP + j] = (_Float16)w;
    }
}

// ---------------- K3: oc = h @ w2h^T  (K=320, N=16) + per-block stat partials
__global__ __launch_bounds__(256) void k_gemm2(const _Float16* __restrict__ h,
                                               const _Float16* __restrict__ w2h,
                                               float* __restrict__ oc,
                                               float* __restrict__ part2)
{
    __shared__ _Float16 Wlds[16][328];   // pad 320->328 to break bank conflicts
    __shared__ float reds[4][16], redq[4][16];
    const int t     = threadIdx.x;
    const int wave  = t >> 6;
    const int lane  = t & 63;
    const int row15 = lane & 15;
    const int quad  = lane >> 4;

    for (int c = t; c < 640; c += 256) { // 16*320/8 chunks
        int r  = c / 40;
        int cc = (c - r * 40) * 8;
        *(half8*)&Wlds[r][cc] = *(const half8*)(w2h + r * NP + cc);
    }
    __syncthreads();

    const int m0 = blockIdx.x * 64 + wave * 16;
    const _Float16* hp = h + (size_t)(m0 + row15) * NP + quad * 8;
    floatx4 acc = {};
#pragma unroll
    for (int kk = 0; kk < NP; kk += 32) {
        half8 a2 = *(const half8*)(hp + kk);
        half8 b2 = *(const half8*)&Wlds[row15][kk + quad * 8];
        acc = __builtin_amdgcn_mfma_f32_16x16x32_f16(a2, b2, acc, 0, 0, 0);
    }
    float s = 0.f, q = 0.f;
#pragma unroll
    for (int r = 0; r < 4; ++r) {
        float v = acc[r];
        oc[(size_t)(m0 + quad * 4 + r) * NP2 + row15] = v;
        s += v; q += v * v;
    }
    s += __shfl_xor(s, 16); s += __shfl_xor(s, 32);
    q += __shfl_xor(q, 16); q += __shfl_xor(q, 32);
    if (lane < 16) { reds[wave][row15] = s; redq[wave][row15] = q; }
    __syncthreads();
    if (t < 16) {
        float S = reds[0][t] + reds[1][t] + reds[2][t] + reds[3][t];
        float Q = redq[0][t] + redq[1][t] + redq[2][t] + redq[3][t];
        part2[(size_t)t * NBLK + blockIdx.x]          = S;
        part2[(size_t)(16 + t) * NBLK + blockIdx.x]   = Q;
    }
}

// ---------------- K4: FUSED reduce#2 + BN2-coefficient precompute
// One block per output col k: reduce sum AND sumsq, write (mean, scale) so
// k_final does no sqrt/div per thread. Same formula as before.
__global__ void k_stat2(const float* __restrict__ part2, const float* __restrict__ gamma2,
                        float* __restrict__ st2)
{
    __shared__ float redS[4], redQ[4];
    const int k = blockIdx.x;            // 0..15
    const int t = threadIdx.x;           // 256
    const float* ps = part2 + (size_t)k * NBLK;
    const float* pq = part2 + (size_t)(16 + k) * NBLK;
    float s = ps[t] + ps[t + 256] + ps[t + 512] + ps[t + 768];
    float q = pq[t] + pq[t + 256] + pq[t + 512] + pq[t + 768];
#pragma unroll
    for (int off = 1; off < 64; off <<= 1) {
        s += __shfl_xor(s, off);
        q += __shfl_xor(q, off);
    }
    if ((t & 63) == 0) { redS[t >> 6] = s; redQ[t >> 6] = q; }
    __syncthreads();
    if (t == 0) {
        float S = redS[0] + redS[1] + redS[2] + redS[3];
        float Q = redQ[0] + redQ[1] + redQ[2] + redQ[3];
        float mean = S * (1.0f / 65536.0f);
        float var  = Q * (1.0f / 65536.0f) - mean * mean;
        float sc   = (k < D_OUT) ? gamma2[k] / sqrtf(var + EPS) : 0.0f;
        st2[k]      = mean;
        st2[16 + k] = sc;
    }
}

// ---------------- K5: BN2 epilogue -> out[65536][10] fp32
__global__ void k_final(const float* __restrict__ oc, const float* __restrict__ st2,
                        const float* __restrict__ beta2, float* __restrict__ out)
{
    int idx = blockIdx.x * 256 + threadIdx.x;    // 2560*256 == 655360 exactly
    int m = idx / 10;
    int k = idx - m * 10;
    float mean = st2[k];
    float sc   = st2[16 + k];
    out[idx] = (oc[(size_t)m * NP2 + k] - mean) * sc + beta2[k];
}

extern "C" void kernel_launch(void* const* d_in, const int* in_sizes, int n_in,
                              void* d_out, int out_size, void* d_ws, size_t ws_size,
                              hipStream_t stream)
{
    const float* x      = (const float*)d_in[0];
    const float* W1     = (const float*)d_in[1];
    const float* gamma1 = (const float*)d_in[2];
    // d_in[3] = beta1 : algebraically cancels under BN2's mean subtraction
    const float* W2     = (const float*)d_in[4];
    const float* gamma2 = (const float*)d_in[5];
    const float* beta2  = (const float*)d_in[6];
    float* out = (float*)d_out;

    char* ws = (char*)d_ws;
    _Float16* S1    = (_Float16*)(ws + OFF_S1);
    _Float16* h     = (_Float16*)(ws + OFF_H);
    _Float16* w2h   = (_Float16*)(ws + OFF_W2);
    float*    st2   = (float*)(ws + OFF_ST2);
    float*    oc    = (float*)(ws + OFF_OC);
    float*    part  = (float*)(ws + OFF_P1);   // aliases oc (time-disjoint)
    float*    part2 = (float*)(ws + OFF_P2);

    k_prep1 <<<1000, 256, 0, stream>>>(W1, S1);
    k_gemm1 <<<NBLK, 256, 0, stream>>>(x, S1, h, part);
    k_stat1 <<<320, 256, 0, stream>>>(part, gamma1, W2, w2h);
    k_gemm2 <<<NBLK, 256, 0, stream>>>(h, w2h, oc, part2);
    k_stat2 <<<16, 256, 0, stream>>>(part2, gamma2, st2);
    k_final <<<2560, 256, 0, stream>>>(oc, st2, beta2, out);
}